// Round 9
// baseline (294.879 us; speedup 1.0000x reference)
//
#include <hip/hip_runtime.h>
#include <stdint.h>

// RNN_autoreg: 2-layer LSTM (B=4096, T=60, H=128), one persistent kernel.
// r9: producer/consumer wave specialization. 256 blocks (1/CU), 1024 threads
// (16 waves), 16 batch rows/block.
//   Waves 0-7  (H): per step, acc <- partial (LDS, per-thread slot), 16 H-MFMAs
//                   (Whh half of weights, 64 VGPR), pointwise, h-write. c stays
//                   in registers all 60 steps.
//   Waves 8-15 (X): one step AHEAD, compute partial(t+1)=bias+Wx.x(t+1) (no h
//                   dep) into the other partial buffer; do all staging, history
//                   stores (plain-layout ws image, r8-verified), out-MLP (wave 8,
//                   wcomb in LDS), prefetch. All latency-tolerant work.
// One barrier/step; barrier counts mirrored exactly between the role blocks.

typedef __bf16 bf16x8 __attribute__((ext_vector_type(8)));
typedef __bf16 bf16x4 __attribute__((ext_vector_type(4)));
typedef float  f32x4  __attribute__((ext_vector_type(4)));

#define HQ      4096u
#define H0_OFF  0u        // H dbuf: 2 x 4096
#define PART    8192u     // partial dbuf: 2 x 32768 ([buf][tid_slot(512)][4 gates][f32x4])
#define PHALF   32768u
#define XD_OFF  73728u    // phase-1 X ring: 4 x 4096 (slot = slice & 3)
#define XA_OFF  90112u    // x-input frags: [60][16] bf16x4 = 7680 B
#define WC_OFF  97792u    // wcomb bf16 [16][128] (rows 4-15 junk, never stored)
#define LDS_SZ  105984

#define S1f (-1.4426950408889634f)   // -log2(e)   for i,f,o gates
#define S2f (-2.8853900817779268f)   // -2*log2(e) for g gate / tanh(c)

__device__ __forceinline__ bf16x8 ldw8s(const float* __restrict__ p, float s){
  float4 a = *(const float4*)p;
  float4 b = *(const float4*)(p+4);
  bf16x8 r;
  r[0]=(__bf16)(a.x*s); r[1]=(__bf16)(a.y*s); r[2]=(__bf16)(a.z*s); r[3]=(__bf16)(a.w*s);
  r[4]=(__bf16)(b.x*s); r[5]=(__bf16)(b.y*s); r[6]=(__bf16)(b.z*s); r[7]=(__bf16)(b.w*s);
  return r;
}
__device__ __forceinline__ void load_w4(bf16x8 (&dst)[4], const float* __restrict__ p, int gg, float s){
  #pragma unroll
  for (int kk=0;kk<4;++kk) dst[kk] = ldw8s(p + kk*32 + gg*8, s);
}
// Raw barrier: LDS visibility only; register-destined global ops stay in flight.
__device__ __forceinline__ void step_barrier(){
  asm volatile("s_waitcnt lgkmcnt(0)\n\ts_barrier" ::: "memory");
}
// Pointwise with exp2-prescaled gates: a0=-L*i, a1=-L*f, a2=-2L*g, a3=-L*o.
__device__ __forceinline__ void lstm_pw(const f32x4& a0, const f32x4& a1,
                                        const f32x4& a2, const f32x4& a3,
                                        float (&c_)[4], float (&hn)[4]){
  #pragma unroll
  for (int i=0;i<4;++i){
    float ei = __builtin_amdgcn_exp2f(a0[i]);
    float ef = __builtin_amdgcn_exp2f(a1[i]);
    float eg = __builtin_amdgcn_exp2f(fminf(a2[i], 126.0f));
    float eo = __builtin_amdgcn_exp2f(a3[i]);
    float sf = __builtin_amdgcn_rcpf(1.0f + ef);
    float itg = (1.0f - eg) * __builtin_amdgcn_rcpf((1.0f + ei)*(1.0f + eg));
    float ci = sf*c_[i] + itg;
    float ec = __builtin_amdgcn_exp2f(S2f*__builtin_fabsf(ci));
    float th = (1.0f - ec) * __builtin_amdgcn_rcpf((1.0f + eo)*(1.0f + ec));
    c_[i] = ci;
    hn[i] = __builtin_copysignf(th, ci);
  }
}

// Fold W_out @ W_lat -> wcomb[4][128], bcomb[4] at wcomb[512..515]
__global__ void comb_kernel(const float* __restrict__ W_lat, const float* __restrict__ b_lat,
                            const float* __restrict__ W_out, const float* __restrict__ b_out,
                            float* __restrict__ wcomb){
  int tid = threadIdx.x;
  int m = tid >> 7, k = tid & 127;
  float s = 0.f;
  for (int a=0;a<128;++a) s += W_out[m*128+a]*W_lat[a*128+k];
  wcomb[tid] = s;
  if (tid < 4){
    float sb = b_out[tid];
    for (int a=0;a<128;++a) sb += W_out[tid*128+a]*b_lat[a];
    wcomb[512+tid] = sb;
  }
}

#define MF(af_,wb_,ac_) ac_ = __builtin_amdgcn_mfma_f32_16x16x32_bf16(af_, wb_, ac_, 0,0,0)
#define BC8(q_) __builtin_bit_cast(bf16x8, q_)

__global__ __launch_bounds__(1024, 1)
void lstm_fused(const float* __restrict__ xmain_g, const float* __restrict__ sfc,
                const float* __restrict__ mem_g, const float* __restrict__ hx2g,
                const float* __restrict__ cx2g,
                const float* __restrict__ Wsfc1, const float* __restrict__ bsfc1,
                const float* __restrict__ Wsfc2, const float* __restrict__ bsfc2,
                const float* __restrict__ Wih1, const float* __restrict__ Whh1,
                const float* __restrict__ bih1, const float* __restrict__ bhh1,
                const float* __restrict__ Wih2, const float* __restrict__ Whh2,
                const float* __restrict__ bih2, const float* __restrict__ bhh2,
                const float* __restrict__ Wso, const float* __restrict__ bso,
                const float* __restrict__ wcomb_ws,
                uint2* __restrict__ ws_u2, float* __restrict__ dout)
{
  __shared__ __align__(16) unsigned char lds[LDS_SZ];
  const int tid = threadIdx.x;
  const int w   = tid >> 6;
  const int l   = tid & 63;
  const int gg  = l >> 4;
  const int l16 = l & 15;
  const int blk = blockIdx.x;
  const int b0  = blk * 16;
  const uint32_t amask = (uint32_t)((l16 & 7) << 4);
  const uint32_t abase = (uint32_t)(l16*256 + gg*16);
  uint2* wsimg = ws_u2 + (size_t)blk * 30720;                   // 60 slices x 512 uint2, plain layout
  const char* wsb = (const char*)wsimg;

  // XA staging: all 1024 threads
  #pragma unroll
  for (int e = tid; e < 960; e += 1024){
    int t = e >> 4, row = e & 15;
    float4 xv = *(const float4*)(xmain_g + (size_t)(b0+row)*240 + t*4);
    bf16x4 b4; b4[0]=(__bf16)xv.x; b4[1]=(__bf16)xv.y; b4[2]=(__bf16)xv.z; b4[3]=(__bf16)xv.w;
    *(bf16x4*)(lds + XA_OFF + (uint32_t)e*8u) = b4;
  }

  if (tid < 512){
    // ===================== H ROLE (waves 0-7) =====================
    const int j = w*16 + l16;
    const int srow = tid >> 5;
    const uint32_t stg_off = (uint32_t)(((srow*256) + (tid&31)*8) ^ ((srow&7)<<4));
    uint32_t hw_off[4];
    #pragma unroll
    for (int i=0;i<4;++i){
      int r = gg*4 + i;
      hw_off[i] = (uint32_t)((r*256 + j*2) ^ ((r&7)<<4));
    }
    { // H-buf[0] <- h1_0 = tanh(sfc @ Wsfc1^T + bsfc1)
      int c0 = (tid&31)*4;
      float4 wa = *(const float4*)(Wsfc1 + c0*3);
      float4 wb = *(const float4*)(Wsfc1 + c0*3 + 4);
      float4 wc = *(const float4*)(Wsfc1 + c0*3 + 8);
      const float* sp = sfc + (size_t)(b0+srow)*3;
      float s0 = sp[0], s1 = sp[1], s2 = sp[2];
      float4 bb = *(const float4*)(bsfc1 + c0);
      float v0 = tanhf(bb.x + s0*wa.x + s1*wa.y + s2*wa.z);
      float v1 = tanhf(bb.y + s0*wa.w + s1*wb.x + s2*wb.y);
      float v2 = tanhf(bb.z + s0*wb.z + s1*wb.w + s2*wc.x);
      float v3 = tanhf(bb.w + s0*wc.y + s1*wc.z + s2*wc.w);
      bf16x4 h4; h4[0]=(__bf16)v0; h4[1]=(__bf16)v1; h4[2]=(__bf16)v2; h4[3]=(__bf16)v3;
      *(bf16x4*)(lds + H0_OFF + stg_off) = h4;
    }
    float c_[4];
    {
      const float* wr = Wsfc2 + j*3;
      float w0_=wr[0], w1_=wr[1], w2_=wr[2];
      float bj = bsfc2[j];
      #pragma unroll
      for (int i=0;i<4;++i){
        const float* sp = sfc + (size_t)(b0 + gg*4 + i)*3;
        c_[i] = tanhf(bj + sp[0]*w0_ + sp[1]*w1_ + sp[2]*w2_);
      }
    }
    bf16x8 wB0[4], wB1[4], wB2[4], wB3[4];     // Whh half only (64 VGPR)
    load_w4(wB0, Whh1 + (size_t)(0*128+j)*128, gg, S1f);
    load_w4(wB1, Whh1 + (size_t)(1*128+j)*128, gg, S1f);
    load_w4(wB2, Whh1 + (size_t)(2*128+j)*128, gg, S2f);
    load_w4(wB3, Whh1 + (size_t)(3*128+j)*128, gg, S1f);
    step_barrier();   // B1
    step_barrier();   // B2: partial(0) ready
    #pragma unroll 1
    for (int t=0; t<60; ++t){
      const uint32_t Hc = H0_OFF + (uint32_t)(t&1)*HQ;
      const uint32_t Pc = PART + (uint32_t)(t&1)*PHALF + (uint32_t)tid*64u;
      f32x4 a0 = *(const f32x4*)(lds + Pc);
      f32x4 a1 = *(const f32x4*)(lds + Pc + 16);
      f32x4 a2 = *(const f32x4*)(lds + Pc + 32);
      f32x4 a3 = *(const f32x4*)(lds + Pc + 48);
      uint4 qh0 = *(const uint4*)(lds + Hc + ((abase       ) ^ amask));
      uint4 qh1 = *(const uint4*)(lds + Hc + ((abase +  64u) ^ amask));
      uint4 qh2 = *(const uint4*)(lds + Hc + ((abase + 128u) ^ amask));
      uint4 qh3 = *(const uint4*)(lds + Hc + ((abase + 192u) ^ amask));
      bf16x8 h0 = BC8(qh0), h1 = BC8(qh1), h2 = BC8(qh2), h3 = BC8(qh3);
      MF(h0,wB0[0],a0); MF(h0,wB1[0],a1); MF(h0,wB2[0],a2); MF(h0,wB3[0],a3);
      MF(h1,wB0[1],a0); MF(h1,wB1[1],a1); MF(h1,wB2[1],a2); MF(h1,wB3[1],a3);
      MF(h2,wB0[2],a0); MF(h2,wB1[2],a1); MF(h2,wB2[2],a2); MF(h2,wB3[2],a3);
      MF(h3,wB0[3],a0); MF(h3,wB1[3],a1); MF(h3,wB2[3],a2); MF(h3,wB3[3],a3);
      float hn[4];
      lstm_pw(a0,a1,a2,a3, c_, hn);
      #pragma unroll
      for (int i=0;i<4;++i)
        *(__bf16*)(lds + H0_OFF + (uint32_t)((t+1)&1)*HQ + hw_off[i]) = (__bf16)hn[i];
      step_barrier();   // B3..B62
    }
    // transition
    load_w4(wB0, Whh2 + (size_t)(0*128+j)*128, gg, S1f);
    load_w4(wB1, Whh2 + (size_t)(1*128+j)*128, gg, S1f);
    load_w4(wB2, Whh2 + (size_t)(2*128+j)*128, gg, S2f);
    load_w4(wB3, Whh2 + (size_t)(3*128+j)*128, gg, S1f);
    #pragma unroll
    for (int i=0;i<4;++i) c_[i] = cx2g[(size_t)(b0 + gg*4 + i)*128 + j];
    step_barrier();   // B63: X done reading H-buf[0] (slice 59)
    { // H-buf[0] <- hx2
      float4 h2v = *(const float4*)(hx2g + (size_t)(b0+srow)*128 + (tid&31)*4);
      bf16x4 h4; h4[0]=(__bf16)h2v.x; h4[1]=(__bf16)h2v.y; h4[2]=(__bf16)h2v.z; h4[3]=(__bf16)h2v.w;
      *(bf16x4*)(lds + H0_OFF + stg_off) = h4;
    }
    step_barrier();   // B64
    #pragma unroll 1
    for (int t=0; t<60; ++t){
      const uint32_t Hc = H0_OFF + (uint32_t)(t&1)*HQ;
      const uint32_t Pc = PART + (uint32_t)(t&1)*PHALF + (uint32_t)tid*64u;
      f32x4 a0 = *(const f32x4*)(lds + Pc);
      f32x4 a1 = *(const f32x4*)(lds + Pc + 16);
      f32x4 a2 = *(const f32x4*)(lds + Pc + 32);
      f32x4 a3 = *(const f32x4*)(lds + Pc + 48);
      uint4 qh0 = *(const uint4*)(lds + Hc + ((abase       ) ^ amask));
      uint4 qh1 = *(const uint4*)(lds + Hc + ((abase +  64u) ^ amask));
      uint4 qh2 = *(const uint4*)(lds + Hc + ((abase + 128u) ^ amask));
      uint4 qh3 = *(const uint4*)(lds + Hc + ((abase + 192u) ^ amask));
      bf16x8 h0 = BC8(qh0), h1 = BC8(qh1), h2 = BC8(qh2), h3 = BC8(qh3);
      MF(h0,wB0[0],a0); MF(h0,wB1[0],a1); MF(h0,wB2[0],a2); MF(h0,wB3[0],a3);
      MF(h1,wB0[1],a0); MF(h1,wB1[1],a1); MF(h1,wB2[1],a2); MF(h1,wB3[1],a3);
      MF(h2,wB0[2],a0); MF(h2,wB1[2],a1); MF(h2,wB2[2],a2); MF(h2,wB3[2],a3);
      MF(h3,wB0[3],a0); MF(h3,wB1[3],a1); MF(h3,wB2[3],a2); MF(h3,wB3[3],a3);
      float hn[4];
      lstm_pw(a0,a1,a2,a3, c_, hn);
      #pragma unroll
      for (int i=0;i<4;++i)
        *(__bf16*)(lds + H0_OFF + (uint32_t)((t+1)&1)*HQ + hw_off[i]) = (__bf16)hn[i];
      step_barrier();   // B65..B124
    }
  } else {
    // ===================== X ROLE (waves 8-15) =====================
    const int xtid = tid - 512;
    const int xw = w - 8;
    const int j = xw*16 + l16;
    const int srow = xtid >> 5;
    const uint32_t stg_off = (uint32_t)(((srow*256) + (xtid&31)*8) ^ ((srow&7)<<4));
    const uint32_t imgoff = (uint32_t)(srow*32 + (xtid&31));
    const uint32_t xfoff = (uint32_t)(l16*256 + gg*16);
    const float* memrow = mem_g + (size_t)(b0 + srow)*7680 + (xtid&31)*4;
    { // ring slots 0,1 <- mem[:,0], mem[:,1]
      float4 m0 = *(const float4*)memrow;
      float4 m1 = *(const float4*)(memrow + 128);
      bf16x4 a4; a4[0]=(__bf16)m0.x; a4[1]=(__bf16)m0.y; a4[2]=(__bf16)m0.z; a4[3]=(__bf16)m0.w;
      bf16x4 b4; b4[0]=(__bf16)m1.x; b4[1]=(__bf16)m1.y; b4[2]=(__bf16)m1.z; b4[3]=(__bf16)m1.w;
      *(bf16x4*)(lds + XD_OFF + stg_off) = a4;
      *(bf16x4*)(lds + XD_OFF + HQ + stg_off) = b4;
    }
    bf16x8 wB0[4], wB1[4], wB2[4], wB3[4];     // Wih half only (K frags 0..3)
    load_w4(wB0, Wih1 + 4 + (size_t)(0*128+j)*132, gg, S1f);
    load_w4(wB1, Wih1 + 4 + (size_t)(1*128+j)*132, gg, S1f);
    load_w4(wB2, Wih1 + 4 + (size_t)(2*128+j)*132, gg, S2f);
    load_w4(wB3, Wih1 + 4 + (size_t)(3*128+j)*132, gg, S1f);
    bf16x8 wxB0 = {}, wxB1 = {}, wxB2 = {}, wxB3 = {};
    if (gg == 0){
      float4 x0 = *(const float4*)(Wih1 + (size_t)(0*128+j)*132);
      float4 x1 = *(const float4*)(Wih1 + (size_t)(1*128+j)*132);
      float4 x2 = *(const float4*)(Wih1 + (size_t)(2*128+j)*132);
      float4 x3 = *(const float4*)(Wih1 + (size_t)(3*128+j)*132);
      wxB0[0]=(__bf16)(x0.x*S1f); wxB0[1]=(__bf16)(x0.y*S1f); wxB0[2]=(__bf16)(x0.z*S1f); wxB0[3]=(__bf16)(x0.w*S1f);
      wxB1[0]=(__bf16)(x1.x*S1f); wxB1[1]=(__bf16)(x1.y*S1f); wxB1[2]=(__bf16)(x1.z*S1f); wxB1[3]=(__bf16)(x1.w*S1f);
      wxB2[0]=(__bf16)(x2.x*S2f); wxB2[1]=(__bf16)(x2.y*S2f); wxB2[2]=(__bf16)(x2.z*S2f); wxB2[3]=(__bf16)(x2.w*S2f);
      wxB3[0]=(__bf16)(x3.x*S1f); wxB3[1]=(__bf16)(x3.y*S1f); wxB3[2]=(__bf16)(x3.z*S1f); wxB3[3]=(__bf16)(x3.w*S1f);
    }
    float b0s = (bih1[0*128+j] + bhh1[0*128+j])*S1f;
    float b1s = (bih1[1*128+j] + bhh1[1*128+j])*S1f;
    float b2s = (bih1[2*128+j] + bhh1[2*128+j])*S2f;
    float b3s = (bih1[3*128+j] + bhh1[3*128+j])*S1f;
    float4 P0 = *(const float4*)(memrow + 2*128);   // mem[2]
    float4 P1 = *(const float4*)(memrow + 3*128);   // mem[3]
    step_barrier();   // B1: ring + H-buf visible
    { // partial(0) = bias + xa(59) + Wx*mem[0] -> PART[0]
      f32x4 a0={b0s,b0s,b0s,b0s}, a1={b1s,b1s,b1s,b1s}, a2={b2s,b2s,b2s,b2s}, a3={b3s,b3s,b3s,b3s};
      bf16x8 xa = {};
      if (gg == 0){
        bf16x4 x4 = *(const bf16x4*)(lds + XA_OFF + (uint32_t)((59<<4) + l16)*8u);
        xa[0]=x4[0]; xa[1]=x4[1]; xa[2]=x4[2]; xa[3]=x4[3];
      }
      MF(xa,wxB0,a0); MF(xa,wxB1,a1); MF(xa,wxB2,a2); MF(xa,wxB3,a3);
      #pragma unroll
      for (int kk=0;kk<4;++kk){
        uint4 q = *(const uint4*)(lds + XD_OFF + ((abase + 64u*(uint32_t)kk) ^ amask));
        bf16x8 af = BC8(q);
        MF(af,wB0[kk],a0); MF(af,wB1[kk],a1); MF(af,wB2[kk],a2); MF(af,wB3[kk],a3);
      }
      const uint32_t pc = PART + (uint32_t)xtid*64u;
      *(f32x4*)(lds + pc)      = a0;
      *(f32x4*)(lds + pc + 16) = a1;
      *(f32x4*)(lds + pc + 32) = a2;
      *(f32x4*)(lds + pc + 48) = a3;
    }
    step_barrier();   // B2
    #pragma unroll 1
    for (int t=0; t<60; ++t){
      if (t >= 1){   // h1 slice t-1 -> ws (plain layout)
        uint2 hv = *(const uint2*)(lds + H0_OFF + (uint32_t)(t&1)*HQ + stg_off);
        wsimg[(size_t)(t-1)*512 + imgoff] = hv;
      }
      if (t < 59){   // partial(t+1): xa(58-t) + Wx*ring[(t+1)&3]
        f32x4 a0={b0s,b0s,b0s,b0s}, a1={b1s,b1s,b1s,b1s}, a2={b2s,b2s,b2s,b2s}, a3={b3s,b3s,b3s,b3s};
        bf16x8 xa = {};
        if (gg == 0){
          bf16x4 x4 = *(const bf16x4*)(lds + XA_OFF + (uint32_t)(((58-t)<<4) + l16)*8u);
          xa[0]=x4[0]; xa[1]=x4[1]; xa[2]=x4[2]; xa[3]=x4[3];
        }
        MF(xa,wxB0,a0); MF(xa,wxB1,a1); MF(xa,wxB2,a2); MF(xa,wxB3,a3);
        const uint32_t xb = XD_OFF + (uint32_t)((t+1)&3)*HQ;
        #pragma unroll
        for (int kk=0;kk<4;++kk){
          uint4 q = *(const uint4*)(lds + xb + ((abase + 64u*(uint32_t)kk) ^ amask));
          bf16x8 af = BC8(q);
          MF(af,wB0[kk],a0); MF(af,wB1[kk],a1); MF(af,wB2[kk],a2); MF(af,wB3[kk],a3);
        }
        const uint32_t pc = PART + (uint32_t)((t+1)&1)*PHALF + (uint32_t)xtid*64u;
        *(f32x4*)(lds + pc)      = a0;
        *(f32x4*)(lds + pc + 16) = a1;
        *(f32x4*)(lds + pc + 32) = a2;
        *(f32x4*)(lds + pc + 48) = a3;
      }
      if (t + 2 <= 59){   // stage mem[t+2] -> ring slot (t+2)&3
        bf16x4 m4; m4[0]=(__bf16)P0.x; m4[1]=(__bf16)P0.y; m4[2]=(__bf16)P0.z; m4[3]=(__bf16)P0.w;
        *(bf16x4*)(lds + XD_OFF + (uint32_t)((t+2)&3)*HQ + stg_off) = m4;
      }
      P0 = P1;
      if (t + 4 <= 59) P1 = *(const float4*)(memrow + (size_t)(t+4)*128);
      step_barrier();   // B3..B62
    }
    // transition
    { // slice 59 = h1(60) in H-buf[0] -> ws; new weights; partial(0) for phase 2
      uint2 hv = *(const uint2*)(lds + H0_OFF + stg_off);
      wsimg[(size_t)59*512 + imgoff] = hv;
      load_w4(wB0, Wih2 + (size_t)(0*128+j)*128, gg, S1f);
      load_w4(wB1, Wih2 + (size_t)(1*128+j)*128, gg, S1f);
      load_w4(wB2, Wih2 + (size_t)(2*128+j)*128, gg, S2f);
      load_w4(wB3, Wih2 + (size_t)(3*128+j)*128, gg, S1f);
      b0s = (bih2[0*128+j] + bhh2[0*128+j])*S1f;
      b1s = (bih2[1*128+j] + bhh2[1*128+j])*S1f;
      b2s = (bih2[2*128+j] + bhh2[2*128+j])*S2f;
      b3s = (bih2[3*128+j] + bhh2[3*128+j])*S1f;
      f32x4 a0={b0s,b0s,b0s,b0s}, a1={b1s,b1s,b1s,b1s}, a2={b2s,b2s,b2s,b2s}, a3={b3s,b3s,b3s,b3s};
      #pragma unroll
      for (int kk=0;kk<4;++kk){   // A = slice 59 read from H-buf[0]
        uint4 q = *(const uint4*)(lds + H0_OFF + ((abase + 64u*(uint32_t)kk) ^ amask));
        bf16x8 af = BC8(q);
        MF(af,wB0[kk],a0); MF(af,wB1[kk],a1); MF(af,wB2[kk],a2); MF(af,wB3[kk],a3);
      }
      const uint32_t pc = PART + (uint32_t)xtid*64u;
      *(f32x4*)(lds + pc)      = a0;
      *(f32x4*)(lds + pc + 16) = a1;
      *(f32x4*)(lds + pc + 32) = a2;
      *(f32x4*)(lds + pc + 48) = a3;
      // wcomb -> LDS (bf16, plain [4][128]; rows 4-15 of WC never stored to dout)
      if (xtid < 512){
        float v = wcomb_ws[xtid];
        *(__bf16*)(lds + WC_OFF + (uint32_t)xtid*2u) = (__bf16)v;
      }
      asm volatile("s_waitcnt vmcnt(0)" ::: "memory");   // drain ws slice stores
    }
    step_barrier();   // B63
    uint4 X0, X1, X2, X3;
    {   // Xset <- slice 58 (for partial(1) at body 0)
      const char* xp = wsb + (size_t)58*4096u + xfoff;
      X0 = *(const uint4*)(xp);      X1 = *(const uint4*)(xp+64);
      X2 = *(const uint4*)(xp+128);  X3 = *(const uint4*)(xp+192);
    }
    const float bc = (l16 < 4) ? wcomb_ws[512 + l16] : 0.f;
    step_barrier();   // B64
    #pragma unroll 1
    for (int t=0; t<60; ++t){
      if (t >= 1 && w == 8){   // out[t-1] from h2(t) = H-buf[t&1]   (slack wave)
        const uint32_t Hc = H0_OFF + (uint32_t)(t&1)*HQ;
        f32x4 ao = {0.f,0.f,0.f,0.f};
        #pragma unroll
        for (int kk=0;kk<4;++kk){
          uint4 qh = *(const uint4*)(lds + Hc + ((abase + 64u*(uint32_t)kk) ^ amask));
          uint4 qw = *(const uint4*)(lds + WC_OFF + (uint32_t)(l16*256 + gg*16 + kk*64));
          ao = __builtin_amdgcn_mfma_f32_16x16x32_bf16(BC8(qh), BC8(qw), ao, 0,0,0);
        }
        if (l16 < 4){
          #pragma unroll
          for (int i=0;i<4;++i)
            dout[(size_t)(b0 + gg*4 + i)*240 + (size_t)(t-1)*4 + l16] = ao[i] + bc;
        }
      }
      if (t < 59){   // partial(t+1) from Xset = slice 58-t
        f32x4 a0={b0s,b0s,b0s,b0s}, a1={b1s,b1s,b1s,b1s}, a2={b2s,b2s,b2s,b2s}, a3={b3s,b3s,b3s,b3s};
        MF(BC8(X0),wB0[0],a0); MF(BC8(X0),wB1[0],a1); MF(BC8(X0),wB2[0],a2); MF(BC8(X0),wB3[0],a3);
        MF(BC8(X1),wB0[1],a0); MF(BC8(X1),wB1[1],a1); MF(BC8(X1),wB2[1],a2); MF(BC8(X1),wB3[1],a3);
        MF(BC8(X2),wB0[2],a0); MF(BC8(X2),wB1[2],a1); MF(BC8(X2),wB2[2],a2); MF(BC8(X2),wB3[2],a3);
        MF(BC8(X3),wB0[3],a0); MF(BC8(X3),wB1[3],a1); MF(BC8(X3),wB2[3],a2); MF(BC8(X3),wB3[3],a3);
        const uint32_t pc = PART + (uint32_t)((t+1)&1)*PHALF + (uint32_t)xtid*64u;
        *(f32x4*)(lds + pc)      = a0;
        *(f32x4*)(lds + pc + 16) = a1;
        *(f32x4*)(lds + pc + 32) = a2;
        *(f32x4*)(lds + pc + 48) = a3;
        if (t <= 57){   // reload Xset <- slice 57-t (used next body)
          const char* xp = wsb + (size_t)(57-t)*4096u + xfoff;
          X0 = *(const uint4*)(xp);      X1 = *(const uint4*)(xp+64);
          X2 = *(const uint4*)(xp+128);  X3 = *(const uint4*)(xp+192);
        }
      }
      step_barrier();   // B65..B124
    }
    // epilogue: out[59] + out_sfc from H-buf[0] = h2(60)   (wave 8)
    if (w == 8){
      bf16x8 wsB[4];
      #pragma unroll
      for (int kk=0;kk<4;++kk){
        bf16x8 v = {};
        if (l16 < 3) v = ldw8s(Wso + l16*128 + kk*32 + gg*8, 1.0f);
        wsB[kk] = v;
      }
      f32x4 ao = {0.f,0.f,0.f,0.f};
      f32x4 as_ = {0.f,0.f,0.f,0.f};
      #pragma unroll
      for (int kk=0;kk<4;++kk){
        uint4 qh = *(const uint4*)(lds + H0_OFF + ((abase + 64u*(uint32_t)kk) ^ amask));
        uint4 qw = *(const uint4*)(lds + WC_OFF + (uint32_t)(l16*256 + gg*16 + kk*64));
        bf16x8 af = BC8(qh);
        ao  = __builtin_amdgcn_mfma_f32_16x16x32_bf16(af, BC8(qw), ao, 0,0,0);
        as_ = __builtin_amdgcn_mfma_f32_16x16x32_bf16(af, wsB[kk], as_, 0,0,0);
      }
      if (l16 < 4){
        #pragma unroll
        for (int i=0;i<4;++i)
          dout[(size_t)(b0 + gg*4 + i)*240 + 59*4 + l16] = ao[i] + bc;
      }
      if (l16 < 3){
        float bs = bso[l16];
        #pragma unroll
        for (int i=0;i<4;++i)
          dout[983040 + (size_t)(b0 + gg*4 + i)*3 + l16] = as_[i] + bs;
      }
    }
  }
}

extern "C" void kernel_launch(void* const* d_in, const int* in_sizes, int n_in,
                              void* d_out, int out_size, void* d_ws, size_t ws_size,
                              hipStream_t stream){
  const float* inputs_main = (const float*)d_in[0];
  const float* inputs_sfc  = (const float*)d_in[1];
  const float* rnn1_mem    = (const float*)d_in[2];
  const float* hx2  = (const float*)d_in[3];
  const float* cx2  = (const float*)d_in[4];
  const float* W_sfc1 = (const float*)d_in[5];
  const float* b_sfc1 = (const float*)d_in[6];
  const float* W_sfc2 = (const float*)d_in[7];
  const float* b_sfc2 = (const float*)d_in[8];
  const float* Wih1 = (const float*)d_in[9];
  const float* Whh1 = (const float*)d_in[10];
  const float* bih1 = (const float*)d_in[11];
  const float* bhh1 = (const float*)d_in[12];
  const float* Wih2 = (const float*)d_in[13];
  const float* Whh2 = (const float*)d_in[14];
  const float* bih2 = (const float*)d_in[15];
  const float* bhh2 = (const float*)d_in[16];
  const float* W_lat = (const float*)d_in[17];
  const float* b_lat = (const float*)d_in[18];
  const float* W_out = (const float*)d_in[19];
  const float* b_out = (const float*)d_in[20];
  const float* W_so  = (const float*)d_in[21];
  const float* b_so  = (const float*)d_in[22];
  float* out = (float*)d_out;
  // ws: h1 history, 256 blocks x 60 slices x 4KB (plain [slice][row][col] bf16)
  //     = 62914560 B; wcomb (516 floats) right after.
  uint2* ws_u2 = (uint2*)d_ws;
  float* wcomb = (float*)((char*)d_ws + 62914560u);

  comb_kernel<<<dim3(1), dim3(512), 0, stream>>>(W_lat, b_lat, W_out, b_out, wcomb);
  lstm_fused<<<dim3(256), dim3(1024), 0, stream>>>(inputs_main, inputs_sfc, rnn1_mem, hx2, cx2,
      W_sfc1, b_sfc1, W_sfc2, b_sfc2, Wih1, Whh1, bih1, bhh1, Wih2, Whh2, bih2, bhh2,
      W_so, b_so, wcomb, ws_u2, out);
}